// Round 2
// baseline (228.412 us; speedup 1.0000x reference)
//
#include <hip/hip_runtime.h>
#include <hip/hip_bf16.h>

// XDeepFM CIN, fused 2-layer MFMA kernel for gfx950.
// Layer 0: M=131072 (b,d), K=1521 (pad 1600), N=128.  Z0 = outer(v,v)
// Layer 1: M=131072,       K=2496 (pad 2560), N=128.  Z1 = outer(v,h)
// Output: out[b, 0:64]  = sum_d relu-L0[:,64:128]
//         out[b, 64:192]= sum_d relu-L1[:,0:128]

using short8 = __attribute__((ext_vector_type(8))) short;
using f32x4  = __attribute__((ext_vector_type(4))) float;

#define ZSTR 168                     // bf16 elems per Z row (336B: 16B-aligned, 2-way bank alias only)
#define V_OFF 0                      // float V[128][40]   = 20480 B
#define Z_OFF 20480                  // bf16  Z[128][168]  = 43008 B
#define H_OFF (20480 + 43008)        // bf16  H[128][64]   = 16384 B
#define SMEM_BYTES (20480 + 43008 + 16384)   // 79872

#define W0_SLICES 50                 // 1600 / 32
#define W1_SLICES 80                 // 2560 / 32
#define W0PK_ELEMS (W0_SLICES * 8 * 64 * 8)   // 204800

__device__ __forceinline__ unsigned short f2bf(float x) {
  __hip_bfloat16 h = __float2bfloat16(x);
  return __builtin_bit_cast(unsigned short, h);
}
__device__ __forceinline__ float bf2f(unsigned short b) {
  unsigned int u = ((unsigned int)b) << 16;
  return __builtin_bit_cast(float, u);
}

// ---------------- W pre-pack: fp32 -> bf16 in MFMA B-fragment order ----------------
// Fragment order: for 32-k slice s, n-block nb (16 cols): lane l holds
// W[k = 32s + (l>>4)*8 + ii][n = nb*16 + (l&15)], ii=0..7 contiguous (16B/lane).
__global__ void pack_w(const float* __restrict__ W0, const float* __restrict__ W1,
                       unsigned short* __restrict__ wpk) {
  int tid = blockIdx.x * 256 + threadIdx.x;
  if (tid < W0PK_ELEMS) {
    int p = tid >> 7, n = tid & 127;          // p in [0,1600)
    int q = p / 160, rem = p - q * 160;       // 4 i-blocks of 40 per slab
    int ib = rem / 40, j = rem - ib * 40;
    int i = q * 4 + ib;
    float val = (i < 39 && j < 39) ? W0[(i * 39 + j) * 128 + n] : 0.f;
    int s = p >> 5, kl = p & 31;
    int lane = ((kl >> 3) << 4) | (n & 15);
    int ii = kl & 7, nb = n >> 4;
    wpk[((s * 8 + nb) * 64 + lane) * 8 + ii] = f2bf(val);
  } else {
    int t = tid - W0PK_ELEMS;
    if (t < 2560 * 128) {
      int p = t >> 7, n = t & 127;            // p in [0,2560)
      int i = p >> 6, j = p & 63;             // k = i*64 + j, exact
      float val = (i < 39) ? W1[(i * 64 + j) * 128 + n] : 0.f;
      int s = p >> 5, kl = p & 31;
      int lane = ((kl >> 3) << 4) | (n & 15);
      int ii = kl & 7, nb = n >> 4;
      wpk[W0PK_ELEMS + ((s * 8 + nb) * 64 + lane) * 8 + ii] = f2bf(val);
    }
  }
}

// ---------------- fused CIN main kernel ----------------
__global__ __launch_bounds__(256) void cin_main(const float* __restrict__ X,
                                                const short8* __restrict__ wpk,
                                                float* __restrict__ out) {
  extern __shared__ char smem[];
  float* V          = (float*)(smem + V_OFF);           // [128][40] fp32, row=(bl*16+d), col=i
  unsigned short* Z = (unsigned short*)(smem + Z_OFF);  // [128][ZSTR] bf16
  unsigned short* H = (unsigned short*)(smem + H_OFF);  // [128][64]  bf16

  const int t    = threadIdx.x;
  const int lane = t & 63;
  const int w    = t >> 6;
  const int wm   = w >> 1, wn = w & 1;     // 2x2 wave grid, each wave 64x64
  const int l15  = lane & 15, l4 = lane >> 4;
  const int b0   = blockIdx.x * 8;

  // ---- stage x tile: x[b0+bl, i, d] -> V[bl*16+d][i] ----
  const float* xb = X + (size_t)b0 * 624;   // 8*39*16 = 4992 floats
  for (int f = t * 4; f < 4992; f += 1024) {
    float4 v4 = *(const float4*)(xb + f);
    int bl = f / 624;
    int rem = f - bl * 624;
    int i = rem >> 4, d0 = rem & 15;
    int r = bl * 16 + d0;
    V[(r + 0) * 40 + i] = v4.x;
    V[(r + 1) * 40 + i] = v4.y;
    V[(r + 2) * 40 + i] = v4.z;
    V[(r + 3) * 40 + i] = v4.w;
  }
  __syncthreads();

  // Z-gen ownership: thread t -> row rg = t>>1, j-half hf = t&1
  const int rg = t >> 1, hf = t & 1;

  // register-cache v_j for layer-0 gen (j half: 20 values, j=39 padded to 0)
  float vj[20];
  #pragma unroll
  for (int jj = 0; jj < 20; jj++) {
    int j = hf * 20 + jj;
    vj[jj] = (j < 39) ? V[rg * 40 + j] : 0.f;
  }

  f32x4 acc[4][4];
  #pragma unroll
  for (int mi = 0; mi < 4; mi++)
    #pragma unroll
    for (int ni = 0; ni < 4; ni++)
      acc[mi][ni] = (f32x4){0.f, 0.f, 0.f, 0.f};

  // ================= layer 0: 10 slabs x 160 k (4 i-blocks of 40) =================
  for (int q = 0; q < 10; q++) {
    __syncthreads();   // Z free
    #pragma unroll
    for (int ib = 0; ib < 4; ib++) {
      int i = q * 4 + ib;
      float vi = (i < 39) ? V[rg * 40 + i] : 0.f;
      #pragma unroll
      for (int g = 0; g < 5; g++) {
        ushort4 pk;
        pk.x = f2bf(vi * vj[g * 4 + 0]);
        pk.y = f2bf(vi * vj[g * 4 + 1]);
        pk.z = f2bf(vi * vj[g * 4 + 2]);
        pk.w = f2bf(vi * vj[g * 4 + 3]);
        *(ushort4*)(&Z[rg * ZSTR + ib * 40 + hf * 20 + g * 4]) = pk;
      }
    }
    __syncthreads();   // Z ready
    #pragma unroll
    for (int ss = 0; ss < 5; ss++) {
      int s = q * 5 + ss;
      short8 a[4];
      #pragma unroll
      for (int mi = 0; mi < 4; mi++) {
        int row = wm * 64 + mi * 16 + l15;
        a[mi] = *(const short8*)(&Z[row * ZSTR + ss * 32 + l4 * 8]);
      }
      #pragma unroll
      for (int ni = 0; ni < 4; ni++) {
        short8 bfrag = wpk[(s * 8 + wn * 4 + ni) * 64 + lane];
        #pragma unroll
        for (int mi = 0; mi < 4; mi++)
          acc[mi][ni] = __builtin_amdgcn_mfma_f32_16x16x32_bf16(a[mi], bfrag, acc[mi][ni], 0, 0, 0);
      }
    }
  }

  // ---- layer-0 epilogue: relu; cols 0..63 -> H (bf16, LDS); cols 64..127 -> out[b,0:64] ----
  if (wn == 0) {
    #pragma unroll
    for (int mi = 0; mi < 4; mi++)
      #pragma unroll
      for (int ni = 0; ni < 4; ni++)
        #pragma unroll
        for (int e = 0; e < 4; e++) {
          int row = wm * 64 + mi * 16 + l4 * 4 + e;
          int col = ni * 16 + l15;
          H[row * 64 + col] = f2bf(fmaxf(acc[mi][ni][e], 0.f));
        }
  } else {
    #pragma unroll
    for (int mi = 0; mi < 4; mi++)
      #pragma unroll
      for (int ni = 0; ni < 4; ni++) {
        float s = fmaxf(acc[mi][ni][0], 0.f) + fmaxf(acc[mi][ni][1], 0.f)
                + fmaxf(acc[mi][ni][2], 0.f) + fmaxf(acc[mi][ni][3], 0.f);
        s += __shfl_xor(s, 16);
        s += __shfl_xor(s, 32);
        if (lane < 16)
          out[(size_t)(b0 + wm * 4 + mi) * 192 + ni * 16 + lane] = s;
      }
  }
  __syncthreads();   // H ready for everyone

  // reset accumulators for layer 1
  #pragma unroll
  for (int mi = 0; mi < 4; mi++)
    #pragma unroll
    for (int ni = 0; ni < 4; ni++)
      acc[mi][ni] = (f32x4){0.f, 0.f, 0.f, 0.f};

  // register-cache h_j (32 values per thread-half)
  float hj[32];
  #pragma unroll
  for (int g = 0; g < 8; g++) {
    ushort4 pk = *(const ushort4*)(&H[rg * 64 + hf * 32 + g * 4]);
    hj[g * 4 + 0] = bf2f(pk.x);
    hj[g * 4 + 1] = bf2f(pk.y);
    hj[g * 4 + 2] = bf2f(pk.z);
    hj[g * 4 + 3] = bf2f(pk.w);
  }

  // ================= layer 1: 20 slabs x 128 k (2 i-blocks of 64) =================
  for (int q = 0; q < 20; q++) {
    __syncthreads();
    #pragma unroll
    for (int ib = 0; ib < 2; ib++) {
      int i = q * 2 + ib;
      float vi = (i < 39) ? V[rg * 40 + i] : 0.f;
      #pragma unroll
      for (int g = 0; g < 8; g++) {
        ushort4 pk;
        pk.x = f2bf(vi * hj[g * 4 + 0]);
        pk.y = f2bf(vi * hj[g * 4 + 1]);
        pk.z = f2bf(vi * hj[g * 4 + 2]);
        pk.w = f2bf(vi * hj[g * 4 + 3]);
        *(ushort4*)(&Z[rg * ZSTR + ib * 64 + hf * 32 + g * 4]) = pk;
      }
    }
    __syncthreads();
    #pragma unroll
    for (int ss = 0; ss < 4; ss++) {
      int s = W0_SLICES + q * 4 + ss;    // W1 slices live right after W0's in wpk
      short8 a[4];
      #pragma unroll
      for (int mi = 0; mi < 4; mi++) {
        int row = wm * 64 + mi * 16 + l15;
        a[mi] = *(const short8*)(&Z[row * ZSTR + ss * 32 + l4 * 8]);
      }
      #pragma unroll
      for (int ni = 0; ni < 4; ni++) {
        short8 bfrag = wpk[(s * 8 + wn * 4 + ni) * 64 + lane];
        #pragma unroll
        for (int mi = 0; mi < 4; mi++)
          acc[mi][ni] = __builtin_amdgcn_mfma_f32_16x16x32_bf16(a[mi], bfrag, acc[mi][ni], 0, 0, 0);
      }
    }
  }

  // ---- layer-1 epilogue: relu, reduce over d, out[b, 64:192] ----
  #pragma unroll
  for (int mi = 0; mi < 4; mi++)
    #pragma unroll
    for (int ni = 0; ni < 4; ni++) {
      float s = fmaxf(acc[mi][ni][0], 0.f) + fmaxf(acc[mi][ni][1], 0.f)
              + fmaxf(acc[mi][ni][2], 0.f) + fmaxf(acc[mi][ni][3], 0.f);
      s += __shfl_xor(s, 16);
      s += __shfl_xor(s, 32);
      if (lane < 16)
        out[(size_t)(b0 + wm * 4 + mi) * 192 + 64 + wn * 64 + ni * 16 + lane] = s;
    }
}

extern "C" void kernel_launch(void* const* d_in, const int* in_sizes, int n_in,
                              void* d_out, int out_size, void* d_ws, size_t ws_size,
                              hipStream_t stream) {
  const float* X  = (const float*)d_in[0];   // [8192,39,16]
  const float* W0 = (const float*)d_in[1];   // [1521,128]
  const float* W1 = (const float*)d_in[2];   // [2496,128]
  float* out = (float*)d_out;                // [8192,192]
  unsigned short* wpk = (unsigned short*)d_ws;  // bf16 packed W0|W1, ~1.04 MB

  // allow >64KB dynamic LDS (79872 B); host-side, not stream-ordered -> graph-safe
  (void)hipFuncSetAttribute((const void*)cin_main,
                            hipFuncAttributeMaxDynamicSharedMemorySize, SMEM_BYTES);

  int total_pack = W0PK_ELEMS + W1_SLICES * 8 * 64 * 8;   // 532480
  pack_w<<<(total_pack + 255) / 256, 256, 0, stream>>>(W0, W1, wpk);
  cin_main<<<1024, 256, SMEM_BYTES, stream>>>(X, (const short8*)wpk, out);
}